// Round 1
// 160.335 us; speedup vs baseline: 1.0448x; 1.0448x over previous
//
#include <hip/hip_runtime.h>

// InvertAffine: per sample, full = [[I+M, t],[0,1]] (4x4). Inverse is
// [[B, -B t],[0,1]] with B = (I+M)^{-1} via 3x3 cofactors.
// 192 MB logical traffic; write-only fill hits 6.75 TB/s on this machine.
//
// R1/R2 post-mortem: coalescing, LDS staging, streaming shape, occupancy all
// neutral -> kernel stuck at ~54-58 us (3.3-3.5 TB/s combined). Nothing
// CU-side saturated (VALU 8%, vmem 5 B/cyc/CU, 0 bank conflicts).
// R3/R5: NT stores — neutral (167.7 -> 167.5). RFO-on-store theory dead.
// R6 theory: the timed region runs right after a 384 MB poison fill whose
// dirty lines sit in L3 (fill drains TCC at 6.75 TB/s > HBM achievable).
// Our read stream ALLOCATES in L2/L3, forcibly evicting those dirty lines
// -> ~96-256 MB of concurrent writeback = the missing bandwidth.
// Fix under test: nontemporal LOADS as well (read-once data, no reuse) so
// the read stream stops evicting dirty poison lines. Single change vs R5.

typedef float nfloat4 __attribute__((ext_vector_type(4)));

__global__ __launch_bounds__(256, 8) void invert_affine_kernel(
    const float4* __restrict__ in, float4* __restrict__ out, int b) {
  __shared__ float4 buf[768];  // 256 samples * 3 float4 = 12 KB

  const int tid = threadIdx.x;
  const int base_s = blockIdx.x * 256;
  const int base_f4 = base_s * 3;
  const int n_f4 = b * 3;

  // coalesced global -> LDS, nontemporal (no L2/L3 allocate: read-once data,
  // avoid evicting the poison fill's dirty L3 lines during our read window)
#pragma unroll
  for (int k = 0; k < 3; ++k) {
    int idx = base_f4 + k * 256 + tid;
    if (idx < n_f4) {
      nfloat4 nv = __builtin_nontemporal_load((const nfloat4*)&in[idx]);
      buf[k * 256 + tid] = make_float4(nv.x, nv.y, nv.z, nv.w);
    }
  }
  __syncthreads();

  const int s = base_s + tid;
  if (s < b) {
    float4 r0 = buf[tid * 3 + 0];
    float4 r1 = buf[tid * 3 + 1];
    float4 r2 = buf[tid * 3 + 2];

    float a00 = r0.x + 1.0f, a01 = r0.y,        a02 = r0.z,        t0 = r0.w;
    float a10 = r1.x,        a11 = r1.y + 1.0f, a12 = r1.z,        t1 = r1.w;
    float a20 = r2.x,        a21 = r2.y,        a22 = r2.z + 1.0f, t2 = r2.w;

    float b00 = a11 * a22 - a12 * a21;
    float b01 = a02 * a21 - a01 * a22;
    float b02 = a01 * a12 - a02 * a11;
    float b10 = a12 * a20 - a10 * a22;
    float b11 = a00 * a22 - a02 * a20;
    float b12 = a02 * a10 - a00 * a12;
    float b20 = a10 * a21 - a11 * a20;
    float b21 = a01 * a20 - a00 * a21;
    float b22 = a00 * a11 - a01 * a10;

    float det = a00 * b00 + a01 * b10 + a02 * b20;
    float rdet = 1.0f / det;

    b00 *= rdet; b01 *= rdet; b02 *= rdet;
    b10 *= rdet; b11 *= rdet; b12 *= rdet;
    b20 *= rdet; b21 *= rdet; b22 *= rdet;

    buf[tid * 3 + 0] = make_float4(b00 - 1.0f, b01, b02,
                                   -(b00 * t0 + b01 * t1 + b02 * t2));
    buf[tid * 3 + 1] = make_float4(b10, b11 - 1.0f, b12,
                                   -(b10 * t0 + b11 * t1 + b12 * t2));
    buf[tid * 3 + 2] = make_float4(b20, b21, b22 - 1.0f,
                                   -(b20 * t0 + b21 * t1 + b22 * t2));
  }
  __syncthreads();

  // coalesced LDS -> global, nontemporal (no L2 allocate / RFO)
#pragma unroll
  for (int k = 0; k < 3; ++k) {
    int idx = base_f4 + k * 256 + tid;
    if (idx < n_f4) {
      float4 vv = buf[k * 256 + tid];
      nfloat4 nv;
      nv.x = vv.x; nv.y = vv.y; nv.z = vv.z; nv.w = vv.w;
      __builtin_nontemporal_store(nv, (nfloat4*)&out[idx]);
    }
  }
}

extern "C" void kernel_launch(void* const* d_in, const int* in_sizes, int n_in,
                              void* d_out, int out_size, void* d_ws, size_t ws_size,
                              hipStream_t stream) {
  const float4* trf = (const float4*)d_in[0];
  float4* out = (float4*)d_out;
  int b = in_sizes[0] / 12;  // 2,000,000 samples
  const int threads = 256;
  int blocks = (b + threads - 1) / threads;  // 7813
  invert_affine_kernel<<<blocks, threads, 0, stream>>>(trf, out, b);
}

// Round 2
// 159.671 us; speedup vs baseline: 1.0492x; 1.0042x over previous
//
#include <hip/hip_runtime.h>

// InvertAffine: per sample, full = [[I+M, t],[0,1]] (4x4). Inverse is
// [[B, -B t],[0,1]] with B = (I+M)^{-1} via 3x3 cofactors.
// 192 MB logical traffic; write-only fill hits 6.75 TB/s; float4 copy 6.29.
//
// R1/R2: coalescing, LDS staging, streaming shape, occupancy all neutral.
// R3/R5: NT stores neutral (RFO theory dead).
// R6: NT loads WIN (-7 us harness, kernel ~54 -> ~45 us): read-stream L2/L3
//     allocation was evicting the poison fill's dirty L3 lines; NT bypass
//     removed that writeback from our window. Still ~4.3 TB/s vs 6.29 copy.
// R7 theory: block-wide __syncthreads forces vmcnt(0) drain + lockstep
//     load/compute/store phases -> memory pipe gaps (earlier: ~5 B/cyc/CU,
//     half the HBM-bound rate). Fix: wave-private LDS regions so the
//     transpose is wave-local (LDS ops in-order within a wave -> no
//     s_barrier, only a compile-time wave_barrier fence), waves drift
//     freely; and 2 samples/thread -> 6 NT loads in flight per lane.

typedef float nfloat4 __attribute__((ext_vector_type(4)));

__global__ __launch_bounds__(256, 6) void invert_affine_kernel(
    const float4* __restrict__ in, float4* __restrict__ out, int b) {
  // 4 waves * 384 float4 = 24 KB; each wave owns buf[wave]: 128 samples.
  __shared__ float4 buf[4][384];

  const int wave = threadIdx.x >> 6;
  const int lane = threadIdx.x & 63;
  float4* wbuf = buf[wave];

  const int s0 = blockIdx.x * 512 + wave * 128;  // wave's first sample
  const int base_f4 = s0 * 3;
  const int n_f4 = b * 3;

  // dense coalesced global -> wave-local LDS, nontemporal (read-once)
#pragma unroll
  for (int k = 0; k < 6; ++k) {
    const int idx = base_f4 + k * 64 + lane;
    if (idx < n_f4) {
      nfloat4 nv = __builtin_nontemporal_load((const nfloat4*)&in[idx]);
      wbuf[k * 64 + lane] = make_float4(nv.x, nv.y, nv.z, nv.w);
    }
  }
  // wave-local transpose: LDS ops from one wave execute in order; this
  // fence only stops the compiler from reordering reads above the writes.
  __builtin_amdgcn_wave_barrier();

#pragma unroll
  for (int si = 0; si < 2; ++si) {
    const int s = s0 + si * 64 + lane;
    if (s < b) {
      const int o = (si * 64 + lane) * 3;  // stride 12 banks: conflict-free
      float4 r0 = wbuf[o + 0];
      float4 r1 = wbuf[o + 1];
      float4 r2 = wbuf[o + 2];

      float a00 = r0.x + 1.0f, a01 = r0.y,        a02 = r0.z,        t0 = r0.w;
      float a10 = r1.x,        a11 = r1.y + 1.0f, a12 = r1.z,        t1 = r1.w;
      float a20 = r2.x,        a21 = r2.y,        a22 = r2.z + 1.0f, t2 = r2.w;

      float b00 = a11 * a22 - a12 * a21;
      float b01 = a02 * a21 - a01 * a22;
      float b02 = a01 * a12 - a02 * a11;
      float b10 = a12 * a20 - a10 * a22;
      float b11 = a00 * a22 - a02 * a20;
      float b12 = a02 * a10 - a00 * a12;
      float b20 = a10 * a21 - a11 * a20;
      float b21 = a01 * a20 - a00 * a21;
      float b22 = a00 * a11 - a01 * a10;

      float det = a00 * b00 + a01 * b10 + a02 * b20;
      float rdet = 1.0f / det;

      b00 *= rdet; b01 *= rdet; b02 *= rdet;
      b10 *= rdet; b11 *= rdet; b12 *= rdet;
      b20 *= rdet; b21 *= rdet; b22 *= rdet;

      wbuf[o + 0] = make_float4(b00 - 1.0f, b01, b02,
                                -(b00 * t0 + b01 * t1 + b02 * t2));
      wbuf[o + 1] = make_float4(b10, b11 - 1.0f, b12,
                                -(b10 * t0 + b11 * t1 + b12 * t2));
      wbuf[o + 2] = make_float4(b20, b21, b22 - 1.0f,
                                -(b20 * t0 + b21 * t1 + b22 * t2));
    }
  }
  __builtin_amdgcn_wave_barrier();

  // wave-local LDS -> dense coalesced global, nontemporal
#pragma unroll
  for (int k = 0; k < 6; ++k) {
    const int idx = base_f4 + k * 64 + lane;
    if (idx < n_f4) {
      const float4 vv = wbuf[k * 64 + lane];
      nfloat4 nv;
      nv.x = vv.x; nv.y = vv.y; nv.z = vv.z; nv.w = vv.w;
      __builtin_nontemporal_store(nv, (nfloat4*)&out[idx]);
    }
  }
}

extern "C" void kernel_launch(void* const* d_in, const int* in_sizes, int n_in,
                              void* d_out, int out_size, void* d_ws, size_t ws_size,
                              hipStream_t stream) {
  const float4* trf = (const float4*)d_in[0];
  float4* out = (float4*)d_out;
  int b = in_sizes[0] / 12;  // 2,000,000 samples
  const int threads = 256;
  const int samples_per_block = 512;  // 2 per thread
  int blocks = (b + samples_per_block - 1) / samples_per_block;  // 3907
  invert_affine_kernel<<<blocks, threads, 0, stream>>>(trf, out, b);
}